// Round 1
// baseline (167.715 us; speedup 1.0000x reference)
//
#include <hip/hip_runtime.h>

#define N_ROWS 8192
#define D_IN   4096
#define D_F    8192

// Radix-4 Hadamard butterfly over two index bits.
// a: both bits clear, b: low bit set, c: high bit set, d: both set.
__device__ __forceinline__ void h4(float& a, float& b, float& c, float& d) {
  float t0 = a + b, t1 = a - b, t2 = c + d, t3 = c - d;
  a = t0 + t2; c = t0 - t2;
  b = t1 + t3; d = t1 - t3;
}

// One block per row. elem index bits [11:0]:
//   i = bits 1:0  (component inside a float4)     -> register H4
//   lane = bits 7:2 (lane id 0..63)                -> 6 shuffle stages
//   wv = bits 9:8  (wave id 0..3)                  -> LDS radix-4 pass
//   c = bits 11:10 (chunk)                         -> register H4
__global__ __launch_bounds__(256, 3) void srht_kernel(
    const float* __restrict__ x,
    const float* __restrict__ rad,
    const int* __restrict__ perm,
    float* __restrict__ out)
{
  __shared__ float zbuf[3][D_IN];   // 48 KiB: FWHT result per degree
  const int t    = threadIdx.x;
  const int lane = t & 63;
  const int wv   = t >> 6;
  const int row  = blockIdx.x;

  // Load x row once: mapping elem = c*1024 + t*4 + i (coalesced float4)
  float xr[4][4];
  {
    const float4* xrow = reinterpret_cast<const float4*>(x) + (size_t)row * (D_IN / 4);
    #pragma unroll
    for (int c = 0; c < 4; ++c) {
      float4 tv = xrow[c * 256 + t];
      xr[c][0] = tv.x; xr[c][1] = tv.y; xr[c][2] = tv.z; xr[c][3] = tv.w;
    }
  }

  #pragma unroll 1
  for (int d = 0; d < 3; ++d) {
    float v[4][4];
    const float4* rrow = reinterpret_cast<const float4*>(rad) + d * (D_IN / 4);
    #pragma unroll
    for (int c = 0; c < 4; ++c) {
      float4 rv = rrow[c * 256 + t];
      v[c][0] = xr[c][0] * rv.x;
      v[c][1] = xr[c][1] * rv.y;
      v[c][2] = xr[c][2] * rv.z;
      v[c][3] = xr[c][3] * rv.w;
    }

    // bits 0,1 (within float4)
    #pragma unroll
    for (int c = 0; c < 4; ++c) h4(v[c][0], v[c][1], v[c][2], v[c][3]);
    // bits 10,11 (across c)
    #pragma unroll
    for (int i = 0; i < 4; ++i) h4(v[0][i], v[1][i], v[2][i], v[3][i]);

    // bits 2..7 via wave shuffles (lane bits 0..5)
    #pragma unroll
    for (int s = 0; s < 6; ++s) {
      const int mask = 1 << s;
      const bool upper = (lane & mask) != 0;
      #pragma unroll
      for (int c = 0; c < 4; ++c) {
        #pragma unroll
        for (int i = 0; i < 4; ++i) {
          float p = __shfl_xor(v[c][i], mask, 64);
          v[c][i] = upper ? (p - v[c][i]) : (v[c][i] + p);
        }
      }
    }

    // write mapping-A results to LDS (conflict-free float4 pattern)
    float4* zd4 = reinterpret_cast<float4*>(zbuf[d]);
    #pragma unroll
    for (int c = 0; c < 4; ++c)
      zd4[c * 256 + t] = make_float4(v[c][0], v[c][1], v[c][2], v[c][3]);

    __syncthreads();

    // bits 8,9: radix-4 pass. Thread (wv, lane) owns float4s
    // {wv*256 + ww*64 + lane : ww=0..3} -> read, H4 across ww, write back.
    // Read+write by the same thread only -> no barrier needed in between.
    float q[4][4];
    #pragma unroll
    for (int ww = 0; ww < 4; ++ww) {
      float4 tv = zd4[wv * 256 + ww * 64 + lane];
      q[ww][0] = tv.x; q[ww][1] = tv.y; q[ww][2] = tv.z; q[ww][3] = tv.w;
    }
    #pragma unroll
    for (int i = 0; i < 4; ++i) h4(q[0][i], q[1][i], q[2][i], q[3][i]);
    #pragma unroll
    for (int ww = 0; ww < 4; ++ww)
      zd4[wv * 256 + ww * 64 + lane] =
          make_float4(q[ww][0], q[ww][1], q[ww][2], q[ww][3]);
    // visibility of this write-back is guaranteed by the next degree's
    // __syncthreads (or the final one below) before anyone reads it.
  }

  __syncthreads();

  // Gather + product. perm is L2-hot (96 KB shared by all rows).
  const float* z0 = zbuf[0];
  const float* z1 = zbuf[1];
  const float* z2 = zbuf[2];
  const float INV = 0.01104854345603981f;  // 1/sqrt(8192)
  const int4* p4 = reinterpret_cast<const int4*>(perm);
  float4* o4 = reinterpret_cast<float4*>(out + (size_t)row * D_F);
  #pragma unroll
  for (int it = 0; it < 8; ++it) {
    int jj = it * 256 + t;            // float4 index within the row
    int4 p0 = p4[jj];
    int4 p1 = p4[2048 + jj];
    int4 p2 = p4[4096 + jj];
    float4 o;
    o.x = z0[p0.x] * z1[p1.x] * z2[p2.x] * INV;
    o.y = z0[p0.y] * z1[p1.y] * z2[p2.y] * INV;
    o.z = z0[p0.z] * z1[p1.z] * z2[p2.z] * INV;
    o.w = z0[p0.w] * z1[p1.w] * z2[p2.w] * INV;
    o4[jj] = o;
  }
}

extern "C" void kernel_launch(void* const* d_in, const int* in_sizes, int n_in,
                              void* d_out, int out_size, void* d_ws, size_t ws_size,
                              hipStream_t stream) {
  const float* x   = (const float*)d_in[0];
  const float* rad = (const float*)d_in[1];
  const int* perm  = (const int*)d_in[2];
  float* out       = (float*)d_out;
  srht_kernel<<<N_ROWS, 256, 0, stream>>>(x, rad, perm, out);
}

// Round 2
// 126.260 us; speedup vs baseline: 1.3283x; 1.3283x over previous
//
#include <hip/hip_runtime.h>

#define N_ROWS 8192
#define D_IN   4096
#define D_F    8192

// Radix-4 Hadamard butterfly over two index bits.
// a: both bits clear, b: low bit set, c: high bit set, d: both set.
__device__ __forceinline__ void h4(float& a, float& b, float& c, float& d) {
  float t0 = a + b, t1 = a - b, t2 = c + d, t3 = c - d;
  a = t0 + t2; c = t0 - t2;
  b = t1 + t3; d = t1 - t3;
}

// One block = one row. 4096 elements, 12 index bits.
// Phase 1 (registers): bits {0,1} (inside float4) x {10,11} (chunk c)
// Phase 2 (LDS transpose): bits {2,3,4,5} in-thread, register H16
// Phase 3 (LDS transpose): bits {6,7,8,9} in-thread, register H16
// LDS swizzle a = e ^ ((e>>4)&0x1C) XORs element bits [8:6] into bank
// bits [4:2]; every transpose access pattern is exactly conflict-free.
// One 16 KiB z-buffer; gather multiplies into per-thread accumulators
// after each degree so all three FWHT results never coexist in LDS.
__global__ __launch_bounds__(256, 4) void srht_kernel(
    const float* __restrict__ x,
    const float* __restrict__ rad,
    const int* __restrict__ perm,
    float* __restrict__ out)
{
  __shared__ __align__(16) float zbuf[D_IN];   // 16 KiB
  const int t   = threadIdx.x;
  const int row = blockIdx.x;

  // Load x row once (coalesced float4): elem e = c*1024 + t*4 + i
  float xr[4][4];
  const float4* xrow = reinterpret_cast<const float4*>(x) + (size_t)row * (D_IN / 4);
  #pragma unroll
  for (int c = 0; c < 4; ++c) {
    float4 tv = xrow[c * 256 + t];
    xr[c][0] = tv.x; xr[c][1] = tv.y; xr[c][2] = tv.z; xr[c][3] = tv.w;
  }

  const float INV = 0.01104854345603981f;  // 1/sqrt(8192)
  float acc[32];
  #pragma unroll
  for (int k = 0; k < 32; ++k) acc[k] = INV;

  // phase-2 base: e2 bits: [1:0]=t[1:0], [7:6]=t[3:2], [9:8]=t[5:4], [11:10]=t[7:6]
  const int e2  = (t & 3) | ((t & 0xFC) << 4);
  const int p2b = e2 ^ ((e2 >> 4) & 0x1C);     // thread-constant swizzled base
  // phase-3 base: e3 bits: [5:0]=t[5:0], [11:10]=t[7:6]
  const int e3  = (t & 0x3F) | ((t & 0xC0) << 4);

  #pragma unroll 1
  for (int d = 0; d < 3; ++d) {
    // ---- multiply by rademacher; register H4 over bits {0,1} and {10,11}
    float v[4][4];
    const float4* rrow = reinterpret_cast<const float4*>(rad) + d * (D_IN / 4);
    #pragma unroll
    for (int c = 0; c < 4; ++c) {
      float4 rv = rrow[c * 256 + t];
      v[c][0] = xr[c][0] * rv.x;
      v[c][1] = xr[c][1] * rv.y;
      v[c][2] = xr[c][2] * rv.z;
      v[c][3] = xr[c][3] * rv.w;
    }
    #pragma unroll
    for (int c = 0; c < 4; ++c) h4(v[c][0], v[c][1], v[c][2], v[c][3]);
    #pragma unroll
    for (int i = 0; i < 4; ++i) h4(v[0][i], v[1][i], v[2][i], v[3][i]);

    __syncthreads();  // previous degree's gather must be done reading zbuf
    // ---- phase-1 write: swizzled float4, conflict-free (8 lanes / 16B slot)
    #pragma unroll
    for (int c = 0; c < 4; ++c) {
      int e = c * 1024 + t * 4;
      int a = e ^ ((e >> 4) & 0x1C);
      *reinterpret_cast<float4*>(&zbuf[a]) =
          make_float4(v[c][0], v[c][1], v[c][2], v[c][3]);
    }
    __syncthreads();

    // ---- phase 2: bits {2,3,4,5} -> register H16 (same-address RMW, no barrier
    //      between read and write)
    float w[16];
    #pragma unroll
    for (int j = 0; j < 16; ++j) w[j] = zbuf[p2b ^ (j << 2)];
    #pragma unroll
    for (int a = 0; a < 4; ++a) h4(w[4*a], w[4*a+1], w[4*a+2], w[4*a+3]);
    #pragma unroll
    for (int b = 0; b < 4; ++b) h4(w[b], w[b+4], w[b+8], w[b+12]);
    #pragma unroll
    for (int j = 0; j < 16; ++j) zbuf[p2b ^ (j << 2)] = w[j];
    __syncthreads();

    // ---- phase 3: bits {6,7,8,9} -> register H16; swizzled read,
    //      then NATURAL write (barrier between: addresses differ)
    #pragma unroll
    for (int j = 0; j < 16; ++j)
      w[j] = zbuf[e3 ^ ((j << 6) | ((j & 7) << 2))];
    #pragma unroll
    for (int a = 0; a < 4; ++a) h4(w[4*a], w[4*a+1], w[4*a+2], w[4*a+3]);
    #pragma unroll
    for (int b = 0; b < 4; ++b) h4(w[b], w[b+4], w[b+8], w[b+12]);
    __syncthreads();
    #pragma unroll
    for (int j = 0; j < 16; ++j) zbuf[e3 + (j << 6)] = w[j];
    __syncthreads();

    // ---- gather this degree into the running product (perm is L2-hot)
    const int4* p4 = reinterpret_cast<const int4*>(perm) + d * (D_F / 4);
    #pragma unroll
    for (int it = 0; it < 8; ++it) {
      int4 p = p4[it * 256 + t];
      acc[it*4+0] *= zbuf[p.x];
      acc[it*4+1] *= zbuf[p.y];
      acc[it*4+2] *= zbuf[p.z];
      acc[it*4+3] *= zbuf[p.w];
    }
  }

  // ---- coalesced float4 output
  float4* o4 = reinterpret_cast<float4*>(out + (size_t)row * D_F);
  #pragma unroll
  for (int it = 0; it < 8; ++it)
    o4[it * 256 + t] =
        make_float4(acc[it*4+0], acc[it*4+1], acc[it*4+2], acc[it*4+3]);
}

extern "C" void kernel_launch(void* const* d_in, const int* in_sizes, int n_in,
                              void* d_out, int out_size, void* d_ws, size_t ws_size,
                              hipStream_t stream) {
  const float* x   = (const float*)d_in[0];
  const float* rad = (const float*)d_in[1];
  const int* perm  = (const int*)d_in[2];
  float* out       = (float*)d_out;
  srht_kernel<<<N_ROWS, 256, 0, stream>>>(x, rad, perm, out);
}